// Round 1
// 215.072 us; speedup vs baseline: 1.0074x; 1.0074x over previous
//
#include <hip/hip_runtime.h>
#include <hip/hip_bf16.h>

// Fused 3-layer tanh RNN (B=131072, T=6, V=31) + linear + tanh + softmax
// on mfma_f32_16x16x32_bf16.
//
// R7: eliminate the LDS transpose from the recurrence entirely.
//
// R6 (83 us/dispatch) was latency-bound: MfmaUtil 4.6%, VALUBusy 42%,
// Occupancy 19%, HBM 14% -- no pipe saturated. The serial chain per layer
// step was MFMA -> tanh -> 8x ds_write -> wave_barrier -> ds_read_b128 ->
// next MFMA (~250 cyc, 18 deep), plus 9 LDS ops/step (bank-conflict 590k).
//
// Fix: operand swap + static W-row permutation.
//   D[n][b] = mfma(A = W-fragment, B = state-fragment)
// puts batch at lane&15 in the C layout (same as the B-operand free dim).
// The n-vs-quad mismatch (C rows are 4q+r, next B-frag needs k=8q+j) is
// absorbed by permuting which W row feeds which A-fragment slot:
//   lo MFMA, A-row i : W row n = 8*(i>>2) + (i&3)
//   hi MFMA, A-row i : W row n = 8*(i>>2) + (i&3) + 4
// so lane (b,q) gets n = 8q..8q+7 in c0[0..3],c1[0..3]; tanh + 4x
// v_cvt_pk_bf16_f32 IS the next B-fragment. No LDS, no shuffles, no
// wave_barrier anywhere in the kernel.
//
// Bias rides the k=31 pad slot (0 extra VGPRs): x-frags carry 1.0 at k=31,
// each layer's pad output row (q3, c1[3]) is forced to 1.0, Wih frags hold
// bf16(bih+bhh) at k=31, Whh frags hold 0 there, Wlin holds blin.
//
// Launch bounds stay (256,1); watch VGPR_Count <= 128 (4 waves/SIMD) and
// WRITE_SIZE == 15.9 MB as the no-spill signature.

#define VD 31
#define TD 6

typedef __attribute__((ext_vector_type(8))) short bf16x8;
typedef __attribute__((ext_vector_type(4))) float f32x4;
typedef __attribute__((ext_vector_type(4))) unsigned u32x4;
typedef float f32x4u __attribute__((ext_vector_type(4), aligned(4)));

struct raw8 { f32x4u a, b; };

__device__ __forceinline__ short f2bf(float f) {
    unsigned u = __float_as_uint(f);
    unsigned r = (u + 0x7fffu + ((u >> 16) & 1u)) >> 16;
    return (short)r;
}

// packed RNE fp32x2 -> bf16x2 (low = lo, high = hi)
__device__ __forceinline__ unsigned f2bf2u(float lo, float hi) {
    union { __hip_bfloat162 h2; unsigned u; } cvt;
    cvt.h2 = __float22bfloat162_rn(make_float2(lo, hi));
    return cvt.u;
}

__device__ __forceinline__ float fast_tanh(float x) {
    x = fminf(fmaxf(x, -15.0f), 15.0f);
    float e = __expf(2.0f * x);
    return (e - 1.0f) * __builtin_amdgcn_rcpf(e + 1.0f);
}

// raw 8-float load at fo = quad3 ? 23 : quad*8 (always in-bounds, 4B aligned)
__device__ __forceinline__ raw8 load_raw(const float* __restrict__ p, int fo) {
    raw8 r;
    r.a = *(const f32x4u*)(p + fo);
    r.b = *(const f32x4u*)(p + fo + 4);
    return r;
}

// raw floats -> B-fragment (lane&15 = batch col, k = quad*8+j). Quad 3
// shifts by one and sets the k=31 pad slot to 1.0 (the bias rides there).
__device__ __forceinline__ bf16x8 cvt_frag(raw8 r, bool q3) {
    float l[8] = {r.a[0], r.a[1], r.a[2], r.a[3], r.b[0], r.b[1], r.b[2], r.b[3]};
    float s[8];
#pragma unroll
    for (int j = 0; j < 7; ++j) s[j] = q3 ? l[j + 1] : l[j];
    s[7] = q3 ? 1.0f : l[7];
    union { u32x4 u4; bf16x8 b8; } cvt;
#pragma unroll
    for (int j = 0; j < 4; ++j) cvt.u4[j] = f2bf2u(s[2 * j], s[2 * j + 1]);
    return cvt.b8;
}

// Permuted-row weight A-fragment: A-row i of the {half} MFMA holds W row
// nn = 8*(i>>2)+(i&3)+4*half, so the C output lands pre-transposed for the
// next step's B-fragment. k=31 slot carries bf16(b1[nn]+b2[nn]); the pad
// row nn==31 is all zero (its output is overridden to 1.0 in layer_step).
__device__ __forceinline__ bf16x8 load_wfrag(const float* __restrict__ W,
                                             const float* __restrict__ b1,
                                             const float* __restrict__ b2,
                                             int i, int half, int k0) {
    const int nn = 8 * (i >> 2) + (i & 3) + 4 * half;
    bf16x8 r;
#pragma unroll
    for (int j = 0; j < 8; ++j) {
        int k = k0 + j;
        float v = 0.0f;
        if (nn < VD) {
            if (k < VD) v = W[nn * VD + k];
            else v = (b1 ? b1[nn] : 0.0f) + (b2 ? b2[nn] : 0.0f);  // k==31
        }
        r[j] = f2bf(v);
    }
    return r;
}

// One RNN layer step for one 16-row tile: 4 MFMA + 8 tanh + 4 cvt_pk.
// Returns the new h directly as the next B-fragment. Pad row (q3, c1[3])
// is forced to 1.0 so the consumer above can pick its bias off k=31.
__device__ __forceinline__ bf16x8 layer_step(bf16x8 x, bf16x8 h,
    bf16x8 wi0, bf16x8 wi1, bf16x8 wh0, bf16x8 wh1, bool q3)
{
    const f32x4 z = {0.0f, 0.0f, 0.0f, 0.0f};
    f32x4 c0 = __builtin_amdgcn_mfma_f32_16x16x32_bf16(wh0, h, z, 0, 0, 0);
    f32x4 c1 = __builtin_amdgcn_mfma_f32_16x16x32_bf16(wh1, h, z, 0, 0, 0);
    c0 = __builtin_amdgcn_mfma_f32_16x16x32_bf16(wi0, x, c0, 0, 0, 0);
    c1 = __builtin_amdgcn_mfma_f32_16x16x32_bf16(wi1, x, c1, 0, 0, 0);
    float t0 = fast_tanh(c0[0]), t1 = fast_tanh(c0[1]);
    float t2 = fast_tanh(c0[2]), t3 = fast_tanh(c0[3]);
    float t4 = fast_tanh(c1[0]), t5 = fast_tanh(c1[1]);
    float t6 = fast_tanh(c1[2]);
    float t7 = q3 ? 1.0f : fast_tanh(c1[3]);
    union { u32x4 u4; bf16x8 b8; } cvt;
    cvt.u4[0] = f2bf2u(t0, t1);
    cvt.u4[1] = f2bf2u(t2, t3);
    cvt.u4[2] = f2bf2u(t4, t5);
    cvt.u4[3] = f2bf2u(t6, t7);
    return cvt.b8;
}

__global__ __launch_bounds__(256, 1) void rnn_mfma(
    const float* __restrict__ inp,   // [B, T, V]
    const float* __restrict__ h0,    // [L, B, V]
    const float* __restrict__ Wih,   // [L, V, V]
    const float* __restrict__ Whh,   // [L, V, V]
    const float* __restrict__ bih,   // [L, V]
    const float* __restrict__ bhh,   // [L, V]
    const float* __restrict__ Wlin,  // [V, V]
    const float* __restrict__ blin,  // [V]
    float* __restrict__ out,         // [B, V]
    int B)
{
    const int wave = threadIdx.x >> 6;
    const int lane = threadIdx.x & 63;
    const int cb   = lane & 15;          // batch column within the 16-row tile
    const int quad = lane >> 4;
    const int k0   = quad * 8;
    const bool q3  = (quad == 3);
    const int fo   = q3 ? 23 : k0;
    const int bbase = (blockIdx.x * 4 + wave) * 32;   // 32 rows per wave
    if (bbase >= B) return;

    // ---- stationary permuted weight A-fragments (56 VGPRs) ----
    const float* W0 = Wih;               const float* U0 = Whh;
    const float* W1 = Wih + VD * VD;     const float* U1 = Whh + VD * VD;
    const float* W2 = Wih + 2 * VD * VD; const float* U2 = Whh + 2 * VD * VD;
    const bf16x8 wiA0 = load_wfrag(W0, bih, bhh, cb, 0, k0);
    const bf16x8 wiA1 = load_wfrag(W0, bih, bhh, cb, 1, k0);
    const bf16x8 whA0 = load_wfrag(U0, nullptr, nullptr, cb, 0, k0);
    const bf16x8 whA1 = load_wfrag(U0, nullptr, nullptr, cb, 1, k0);
    const bf16x8 wiB0 = load_wfrag(W1, bih + VD, bhh + VD, cb, 0, k0);
    const bf16x8 wiB1 = load_wfrag(W1, bih + VD, bhh + VD, cb, 1, k0);
    const bf16x8 whB0 = load_wfrag(U1, nullptr, nullptr, cb, 0, k0);
    const bf16x8 whB1 = load_wfrag(U1, nullptr, nullptr, cb, 1, k0);
    const bf16x8 wiC0 = load_wfrag(W2, bih + 2 * VD, bhh + 2 * VD, cb, 0, k0);
    const bf16x8 wiC1 = load_wfrag(W2, bih + 2 * VD, bhh + 2 * VD, cb, 1, k0);
    const bf16x8 whC0 = load_wfrag(U2, nullptr, nullptr, cb, 0, k0);
    const bf16x8 whC1 = load_wfrag(U2, nullptr, nullptr, cb, 1, k0);
    const bf16x8 wl0  = load_wfrag(Wlin, blin, nullptr, cb, 0, k0);
    const bf16x8 wl1  = load_wfrag(Wlin, blin, nullptr, cb, 1, k0);

    // ---- initial hidden states as B-fragments (pad slot value is a
    //      don't-care at t=0: Whh frags hold 0 at k=31) ----
    bf16x8 h1a = cvt_frag(load_raw(h0 + ((size_t)0 * B + bbase + cb) * VD, fo), q3);
    bf16x8 h1b = cvt_frag(load_raw(h0 + ((size_t)0 * B + bbase + 16 + cb) * VD, fo), q3);
    bf16x8 h2a = cvt_frag(load_raw(h0 + ((size_t)1 * B + bbase + cb) * VD, fo), q3);
    bf16x8 h2b = cvt_frag(load_raw(h0 + ((size_t)1 * B + bbase + 16 + cb) * VD, fo), q3);
    bf16x8 h3a = cvt_frag(load_raw(h0 + ((size_t)2 * B + bbase + cb) * VD, fo), q3);
    bf16x8 h3b = cvt_frag(load_raw(h0 + ((size_t)2 * B + bbase + 16 + cb) * VD, fo), q3);

    const float* xrow0 = inp + (size_t)(bbase + cb) * TD * VD;
    const float* xrow1 = inp + (size_t)(bbase + 16 + cb) * TD * VD;

    raw8 rx0 = load_raw(xrow0, fo);
    raw8 rx1 = load_raw(xrow1, fo);

    for (int t = 0; t < TD; ++t) {
        bf16x8 ax0 = cvt_frag(rx0, q3);
        bf16x8 ax1 = cvt_frag(rx1, q3);
        if (t + 1 < TD) {   // prefetch next-t raw x across the 6 steps below
            rx0 = load_raw(xrow0 + (t + 1) * VD, fo);
            rx1 = load_raw(xrow1 + (t + 1) * VD, fo);
        }
        h1a = layer_step(ax0, h1a, wiA0, wiA1, whA0, whA1, q3);
        h1b = layer_step(ax1, h1b, wiA0, wiA1, whA0, whA1, q3);
        h2a = layer_step(h1a, h2a, wiB0, wiB1, whB0, whB1, q3);
        h2b = layer_step(h1b, h2b, wiB0, wiB1, whB0, whB1, q3);
        h3a = layer_step(h2a, h3a, wiC0, wiC1, whC0, whC1, q3);
        h3b = layer_step(h2b, h3b, wiC0, wiC1, whC0, whC1, q3);
    }

    // ---- final linear + tanh + softmax (over n, i.e. across quads) ----
    const f32x4 z = {0.0f, 0.0f, 0.0f, 0.0f};
#pragma unroll
    for (int tb = 0; tb < 2; ++tb) {
        bf16x8 h3 = tb ? h3b : h3a;
        f32x4 c0 = __builtin_amdgcn_mfma_f32_16x16x32_bf16(wl0, h3, z, 0, 0, 0);
        f32x4 c1 = __builtin_amdgcn_mfma_f32_16x16x32_bf16(wl1, h3, z, 0, 0, 0);
        // lane (cb, q) holds y[n] for n = 8q..8q+7; n==31 (q3, c1[3]) is the
        // pad row -> y = tanh(0) = 0, excluded from the sum (harmless in max:
        // the stabilizer just needs to be column-uniform).
        float v0 = fast_tanh(c0[0]), v1 = fast_tanh(c0[1]);
        float v2 = fast_tanh(c0[2]), v3 = fast_tanh(c0[3]);
        float v4 = fast_tanh(c1[0]), v5 = fast_tanh(c1[1]);
        float v6 = fast_tanh(c1[2]), v7 = fast_tanh(c1[3]);
        float mx = fmaxf(fmaxf(fmaxf(v0, v1), fmaxf(v2, v3)),
                         fmaxf(fmaxf(v4, v5), fmaxf(v6, v7)));
        mx = fmaxf(mx, __shfl_xor(mx, 16));
        mx = fmaxf(mx, __shfl_xor(mx, 32));
        float e0 = __expf(v0 - mx), e1 = __expf(v1 - mx);
        float e2 = __expf(v2 - mx), e3 = __expf(v3 - mx);
        float e4 = __expf(v4 - mx), e5 = __expf(v5 - mx);
        float e6 = __expf(v6 - mx);
        float e7 = q3 ? 0.0f : __expf(v7 - mx);
        float s = ((e0 + e1) + (e2 + e3)) + ((e4 + e5) + (e6 + e7));
        s += __shfl_xor(s, 16);
        s += __shfl_xor(s, 32);
        const float inv = __builtin_amdgcn_rcpf(s);
        const size_t row = (size_t)(bbase + tb * 16 + cb);
        float* po = out + row * VD + k0;            // n = 8q..8q+7, contiguous
        f32x4u lo = {e0 * inv, e1 * inv, e2 * inv, e3 * inv};
        *(f32x4u*)po = lo;
        if (!q3) {
            f32x4u hi = {e4 * inv, e5 * inv, e6 * inv, e7 * inv};
            *(f32x4u*)(po + 4) = hi;
        } else {                                    // n = 28,29,30 only
            po[4] = e4 * inv;
            po[5] = e5 * inv;
            po[6] = e6 * inv;
        }
    }
}

extern "C" void kernel_launch(void* const* d_in, const int* in_sizes, int n_in,
                              void* d_out, int out_size, void* d_ws, size_t ws_size,
                              hipStream_t stream) {
    const float* inp  = (const float*)d_in[0];
    const float* h0   = (const float*)d_in[1];
    const float* Wih  = (const float*)d_in[2];
    const float* Whh  = (const float*)d_in[3];
    const float* bih  = (const float*)d_in[4];
    const float* bhh  = (const float*)d_in[5];
    const float* Wlin = (const float*)d_in[6];
    const float* blin = (const float*)d_in[7];
    float* out = (float*)d_out;

    const int B = in_sizes[0] / (TD * VD);
    const int grid = (B + 127) / 128;    // 128 rows per block (4 waves x 32)
    rnn_mfma<<<grid, 256, 0, stream>>>(inp, h0, Wih, Whh, bih, bhh, Wlin, blin, out, B);
}